// Round 3
// baseline (676.895 us; speedup 1.0000x reference)
//
#include <hip/hip_runtime.h>
#include <hip/hip_bf16.h>

typedef __attribute__((ext_vector_type(8))) short short8;
typedef __attribute__((ext_vector_type(4))) float f32x4;

#define NB 8
#define NS 1024
#define NH 12
#define ND 64
#define NHID 768
#define N3 2304

__device__ __forceinline__ unsigned short f2bf(float f) {
  __hip_bfloat16 h = __float2bfloat16(f);
  return *reinterpret_cast<unsigned short*>(&h);
}
__device__ __forceinline__ float bf2f(unsigned short u) {
  __hip_bfloat16 h;
  *reinterpret_cast<unsigned short*>(&h) = u;
  return __bfloat162float(h);
}

// ---- cast hidden f32 -> bf16 ----
__global__ void k_cast(const float* __restrict__ in, unsigned short* __restrict__ out, int n4) {
  int i = blockIdx.x * blockDim.x + threadIdx.x;
  if (i >= n4) return;
  float4 v = ((const float4*)in)[i];
  ushort4 o;
  o.x = f2bf(v.x); o.y = f2bf(v.y); o.z = f2bf(v.z); o.w = f2bf(v.w);
  ((ushort4*)out)[i] = o;
}

// ---- transpose-cast W [768][2304] f32 -> Wt [2304][768] bf16 ----
__global__ __launch_bounds__(256) void k_wt(const float* __restrict__ W, unsigned short* __restrict__ Wt) {
  __shared__ float tile[32][33];
  int r0 = blockIdx.x * 32;   // over 768
  int c0 = blockIdx.y * 32;   // over 2304
  int tx = threadIdx.x & 31, ty = threadIdx.x >> 5;
#pragma unroll
  for (int p = 0; p < 4; ++p)
    tile[ty + 8*p][tx] = W[(size_t)(r0 + ty + 8*p) * N3 + c0 + tx];
  __syncthreads();
#pragma unroll
  for (int p = 0; p < 4; ++p)
    Wt[(size_t)(c0 + ty + 8*p) * NHID + r0 + tx] = f2bf(tile[tx][ty + 8*p]);
}

// ---- QKV GEMM: [8192][768]bf16 @ Wt[2304][768]bf16 -> qkv [8192][2304]bf16 ----
__global__ __launch_bounds__(256) void k_qkv(const unsigned short* __restrict__ A,
                                             const unsigned short* __restrict__ Wt,
                                             const float* __restrict__ qb,
                                             const float* __restrict__ vb,
                                             unsigned short* __restrict__ out) {
  const int t = threadIdx.x;
  const int w = t >> 6, l = t & 63, l15 = l & 15, lhi = l >> 4;
  const int rowbase = blockIdx.x * 128 + w * 32;
  const int colbase = blockIdx.y * 64;

  f32x4 acc[2][4] = {};
  const unsigned short* arow0 = A + (size_t)(rowbase + l15) * NHID;
  const unsigned short* arow1 = A + (size_t)(rowbase + 16 + l15) * NHID;
  const unsigned short* wrows[4];
#pragma unroll
  for (int n = 0; n < 4; ++n)
    wrows[n] = Wt + (size_t)(colbase + n * 16 + l15) * NHID;

  for (int k0 = 0; k0 < NHID; k0 += 32) {
    short8 a0 = *(const short8*)(arow0 + k0 + lhi * 8);
    short8 a1 = *(const short8*)(arow1 + k0 + lhi * 8);
#pragma unroll
    for (int n = 0; n < 4; ++n) {
      short8 bfr = *(const short8*)(wrows[n] + k0 + lhi * 8);
      acc[0][n] = __builtin_amdgcn_mfma_f32_16x16x32_bf16(a0, bfr, acc[0][n], 0, 0, 0);
      acc[1][n] = __builtin_amdgcn_mfma_f32_16x16x32_bf16(a1, bfr, acc[1][n], 0, 0, 0);
    }
  }
  const int seg = colbase / NHID;   // uniform per block: 0=q 1=k 2=v
#pragma unroll
  for (int n = 0; n < 4; ++n) {
    int col = colbase + n * 16 + l15;
    int cc = col % NHID;
    float bias = (seg == 0) ? qb[cc] : (seg == 2) ? vb[cc] : 0.0f;
#pragma unroll
    for (int m = 0; m < 2; ++m) {
#pragma unroll
      for (int r = 0; r < 4; ++r) {
        int row = rowbase + m * 16 + lhi * 4 + r;
        float v = acc[m][n][r];
        if (seg == 0) v = (v + bias) * 0.125f;
        else if (seg == 2) v = v + bias;
        out[(size_t)row * N3 + col] = f2bf(v);
      }
    }
  }
}

// ---- transpose V (cols 1536..2303 of qkv) -> Vt [96][64][1024] bf16 ----
__global__ __launch_bounds__(256) void k_vt(const unsigned short* __restrict__ qkvb,
                                            unsigned short* __restrict__ Vt) {
  __shared__ unsigned short tile[32][33];
  int s0 = blockIdx.x * 32;  // over 1024
  int d0 = blockIdx.y * 32;  // over 64
  int bh = blockIdx.z;       // 0..95
  int b = bh / NH;
  int hcol = (bh % NH) * ND;
  int tx = threadIdx.x & 31, ty = threadIdx.x >> 5;
#pragma unroll
  for (int p = 0; p < 4; ++p) {
    int s = s0 + ty + 8*p;
    tile[ty + 8*p][tx] = qkvb[(size_t)(b * NS + s) * N3 + 2 * NHID + hcol + d0 + tx];
  }
  __syncthreads();
#pragma unroll
  for (int p = 0; p < 4; ++p) {
    int d = d0 + ty + 8*p;
    Vt[((size_t)bh * ND + d) * NS + s0 + tx] = tile[tx][ty + 8*p];
  }
}

// ---- fused attention: one block per (qtile16, h, b), 8 waves x 128 keys ----
// Swapped QK^T: sc = mfma(K, Q) -> lane q-row = l15, keys kc..kc+3 consecutive
// -> rel/rel2/mask load as float4/int4. p_lds swizzle col ^ (l15<<2).
// After all P reads, p_lds is reused as the f32 ctx-partial buffer [8][16][64].
__global__ __launch_bounds__(512, 8) void k_attn(const unsigned short* __restrict__ qkvb,
                                                 const unsigned short* __restrict__ Vt,
                                                 const float* __restrict__ relp,
                                                 const float* __restrict__ rel2,
                                                 const int* __restrict__ mask,
                                                 float* __restrict__ outp) {
  __shared__ __align__(16) unsigned short p_lds[16][1024];  // 32 KB; reused as f32[8][16][64]
  __shared__ float rs_lds[8][16];
  __shared__ float inv_lds[16];

  const int qt = blockIdx.x, h = blockIdx.y, b = blockIdx.z;
  const int t = threadIdx.x, w = t >> 6, l = t & 63, l15 = l & 15, lhi = l >> 4;
  const int bh = b * NH + h;
  const int swz = l15 << 2;

  // Q fragments (16 rows x 64 d); q already scaled+biased in k_qkv
  const unsigned short* qrowp = qkvb + (size_t)(b * NS + qt * 16 + l15) * N3 + h * ND;
  short8 qa0 = *(const short8*)(qrowp + lhi * 8);
  short8 qa1 = *(const short8*)(qrowp + 32 + lhi * 8);

  const float* relrow  = relp + ((size_t)bh * NS + qt * 16 + l15) * NS;
  const float* rel2row = rel2 + ((size_t)bh * NS + qt * 16 + l15) * NS;
  const int* maskb = mask + b * NS;

  // phase 1: scores -> exp -> p_lds (wave w owns keys w*128 .. w*128+127)
  float rs = 0.f;
#pragma unroll 2
  for (int c = 0; c < 8; ++c) {
    int kb = w * 128 + c * 16;
    const unsigned short* krowp = qkvb + (size_t)(b * NS + kb + l15) * N3 + NHID + h * ND;
    short8 kf0 = *(const short8*)(krowp + lhi * 8);
    short8 kf1 = *(const short8*)(krowp + 32 + lhi * 8);
    f32x4 sc = {};
    sc = __builtin_amdgcn_mfma_f32_16x16x32_bf16(kf0, qa0, sc, 0, 0, 0);
    sc = __builtin_amdgcn_mfma_f32_16x16x32_bf16(kf1, qa1, sc, 0, 0, 0);
    int kc = kb + lhi * 4;
    float4 r4  = *(const float4*)(relrow + kc);
    float4 r24 = *(const float4*)(rel2row + kc);
    int4  m4   = *(const int4*)(maskb + kc);
    float p0 = m4.x ? 0.f : __expf(sc[0] + r4.x + r24.x);
    float p1 = m4.y ? 0.f : __expf(sc[1] + r4.y + r24.y);
    float p2 = m4.z ? 0.f : __expf(sc[2] + r4.z + r24.z);
    float p3 = m4.w ? 0.f : __expf(sc[3] + r4.w + r24.w);
    rs += (p0 + p1) + (p2 + p3);
    ushort4 pw;
    pw.x = f2bf(p0); pw.y = f2bf(p1); pw.z = f2bf(p2); pw.w = f2bf(p3);
    *(ushort4*)(&p_lds[l15][kc ^ swz]) = pw;
  }

  // row sums: reduce lhi-groups within wave, then across 8 waves
  rs += __shfl_xor(rs, 16);
  rs += __shfl_xor(rs, 32);
  if (lhi == 0) rs_lds[w][l15] = rs;
  __syncthreads();
  if (t < 16) {
    float s = 0.f;
#pragma unroll
    for (int ww = 0; ww < 8; ++ww) s += rs_lds[ww][t];
    inv_lds[t] = 1.0f / s;
  }
  __syncthreads();

  // phase 2: PV over own 128 keys, all 16 q-rows x 64 d (partials in regs)
  f32x4 cacc[4] = {};
  const unsigned short* vtb = Vt + (size_t)bh * ND * NS;
#pragma unroll
  for (int c2 = 0; c2 < 4; ++c2) {
    int kb2 = w * 128 + c2 * 32 + lhi * 8;
    ushort4 pa0 = *(const ushort4*)(&p_lds[l15][kb2 ^ swz]);
    ushort4 pa1 = *(const ushort4*)(&p_lds[l15][(kb2 + 4) ^ swz]);
    short8 pa;
    pa[0] = pa0.x; pa[1] = pa0.y; pa[2] = pa0.z; pa[3] = pa0.w;
    pa[4] = pa1.x; pa[5] = pa1.y; pa[6] = pa1.z; pa[7] = pa1.w;
#pragma unroll
    for (int n = 0; n < 4; ++n) {
      short8 vf = *(const short8*)(vtb + (size_t)(n * 16 + l15) * NS + kb2);
      cacc[n] = __builtin_amdgcn_mfma_f32_16x16x32_bf16(pa, vf, cacc[n], 0, 0, 0);
    }
  }

  // probs out: [B,H,S,S] f32, float4 stores (wave w writes rows 2w, 2w+1)
  {
    float* probs = outp + (size_t)NB * NS * NHID;
#pragma unroll
    for (int rr = 0; rr < 2; ++rr) {
      int row = w * 2 + rr;
      float inv = inv_lds[row];
      int sz = row << 2;
      size_t base = ((size_t)bh * NS + qt * 16 + row) * NS;
#pragma unroll
      for (int i = 0; i < 4; ++i) {
        int col = 4 * l + 256 * i;
        ushort4 pv = *(const ushort4*)(&p_lds[row][col ^ sz]);
        float4 o;
        o.x = bf2f(pv.x) * inv;
        o.y = bf2f(pv.y) * inv;
        o.z = bf2f(pv.z) * inv;
        o.w = bf2f(pv.w) * inv;
        *(float4*)(&probs[base + col]) = o;
      }
    }
  }

  // all P reads done -> reuse p_lds as f32 ctx partials [8][16][64]
  __syncthreads();
  float* cpart = (float*)p_lds;
#pragma unroll
  for (int n = 0; n < 4; ++n)
#pragma unroll
    for (int r = 0; r < 4; ++r)
      cpart[w * 1024 + (lhi * 4 + r) * 64 + n * 16 + l15] = cacc[n][r];
  __syncthreads();

  // reduce 8 partials, scale, store ctx [B,S,HID]
#pragma unroll
  for (int i = 0; i < 2; ++i) {
    int idx = t + 512 * i;
    int q = idx >> 6, d = idx & 63;
    float s = 0.f;
#pragma unroll
    for (int ww = 0; ww < 8; ++ww) s += cpart[ww * 1024 + idx];
    outp[(size_t)(b * NS + qt * 16 + q) * NHID + h * ND + d] = s * inv_lds[q];
  }
}

extern "C" void kernel_launch(void* const* d_in, const int* in_sizes, int n_in,
                              void* d_out, int out_size, void* d_ws, size_t ws_size,
                              hipStream_t stream) {
  const float* hidden = (const float*)d_in[0];
  const int* mask = (const int*)d_in[1];
  const float* relp = (const float*)d_in[2];
  const float* rel2 = (const float*)d_in[3];
  const float* Wq = (const float*)d_in[4];
  const float* qb = (const float*)d_in[5];
  const float* vb = (const float*)d_in[6];
  float* out = (float*)d_out;

  const size_t OFF_AHS = 0;                       // 8192*768*2
  const size_t OFF_WT  = 12582912;                // 2304*768*2
  const size_t OFF_QKV = 16121856;                // 8192*2304*2
  const size_t OFF_VT  = 53870592;                // 96*64*1024*2
  if (ws_size < 66453504) return;

  char* ws = (char*)d_ws;
  unsigned short* Ahs  = (unsigned short*)(ws + OFF_AHS);
  unsigned short* Wt   = (unsigned short*)(ws + OFF_WT);
  unsigned short* qkvb = (unsigned short*)(ws + OFF_QKV);
  unsigned short* Vt   = (unsigned short*)(ws + OFF_VT);

  k_cast<<<dim3(6144), dim3(256), 0, stream>>>(hidden, Ahs, (NB * NS * NHID) / 4);
  k_wt<<<dim3(24, 72), dim3(256), 0, stream>>>(Wq, Wt);
  k_qkv<<<dim3(64, 36), dim3(256), 0, stream>>>(Ahs, Wt, qb, vb, qkvb);
  k_vt<<<dim3(32, 2, 96), dim3(256), 0, stream>>>(qkvb, Vt);
  k_attn<<<dim3(64, 12, 8), dim3(512), 0, stream>>>(qkvb, Vt, relp, rel2, mask, out);
}

// Round 4
// 606.420 us; speedup vs baseline: 1.1162x; 1.1162x over previous
//
#include <hip/hip_runtime.h>
#include <hip/hip_bf16.h>

typedef __attribute__((ext_vector_type(8))) short short8;
typedef __attribute__((ext_vector_type(4))) float f32x4;

#define NB 8
#define NS 1024
#define NH 12
#define ND 64
#define NHID 768
#define N3 2304

__device__ __forceinline__ unsigned short f2bf(float f) {
  __hip_bfloat16 h = __float2bfloat16(f);
  return *reinterpret_cast<unsigned short*>(&h);
}
__device__ __forceinline__ float bf2f(unsigned short u) {
  __hip_bfloat16 h;
  *reinterpret_cast<unsigned short*>(&h) = u;
  return __bfloat162float(h);
}

// ---- cast hidden f32 -> bf16 ----
__global__ void k_cast(const float* __restrict__ in, unsigned short* __restrict__ out, int n4) {
  int i = blockIdx.x * blockDim.x + threadIdx.x;
  if (i >= n4) return;
  float4 v = ((const float4*)in)[i];
  ushort4 o;
  o.x = f2bf(v.x); o.y = f2bf(v.y); o.z = f2bf(v.z); o.w = f2bf(v.w);
  ((ushort4*)out)[i] = o;
}

// ---- pack mask [B][S] int -> bitmask [B][16] u64 ----
__global__ void k_mask(const int* __restrict__ mask, unsigned long long* __restrict__ bits) {
  int b = blockIdx.x, t = threadIdx.x;
  unsigned long long bal = __ballot(mask[b * NS + t] != 0);
  if ((t & 63) == 0) bits[b * 16 + (t >> 6)] = bal;
}

// ---- transpose-cast W [768][2304] f32 -> Wt [2304][768] bf16 ----
__global__ __launch_bounds__(256) void k_wt(const float* __restrict__ W, unsigned short* __restrict__ Wt) {
  __shared__ float tile[32][33];
  int r0 = blockIdx.x * 32;   // over 768
  int c0 = blockIdx.y * 32;   // over 2304
  int tx = threadIdx.x & 31, ty = threadIdx.x >> 5;
#pragma unroll
  for (int p = 0; p < 4; ++p)
    tile[ty + 8*p][tx] = W[(size_t)(r0 + ty + 8*p) * N3 + c0 + tx];
  __syncthreads();
#pragma unroll
  for (int p = 0; p < 4; ++p)
    Wt[(size_t)(c0 + ty + 8*p) * NHID + r0 + tx] = f2bf(tile[tx][ty + 8*p]);
}

// ---- QKV GEMM: [8192][768]bf16 @ Wt[2304][768]bf16 -> qkv [8192][2304]bf16 ----
__global__ __launch_bounds__(256) void k_qkv(const unsigned short* __restrict__ A,
                                             const unsigned short* __restrict__ Wt,
                                             const float* __restrict__ qb,
                                             const float* __restrict__ vb,
                                             unsigned short* __restrict__ out) {
  const int t = threadIdx.x;
  const int w = t >> 6, l = t & 63, l15 = l & 15, lhi = l >> 4;
  const int rowbase = blockIdx.x * 128 + w * 32;
  const int colbase = blockIdx.y * 64;

  f32x4 acc[2][4] = {};
  const unsigned short* arow0 = A + (size_t)(rowbase + l15) * NHID;
  const unsigned short* arow1 = A + (size_t)(rowbase + 16 + l15) * NHID;
  const unsigned short* wrows[4];
#pragma unroll
  for (int n = 0; n < 4; ++n)
    wrows[n] = Wt + (size_t)(colbase + n * 16 + l15) * NHID;

  for (int k0 = 0; k0 < NHID; k0 += 32) {
    short8 a0 = *(const short8*)(arow0 + k0 + lhi * 8);
    short8 a1 = *(const short8*)(arow1 + k0 + lhi * 8);
#pragma unroll
    for (int n = 0; n < 4; ++n) {
      short8 bfr = *(const short8*)(wrows[n] + k0 + lhi * 8);
      acc[0][n] = __builtin_amdgcn_mfma_f32_16x16x32_bf16(a0, bfr, acc[0][n], 0, 0, 0);
      acc[1][n] = __builtin_amdgcn_mfma_f32_16x16x32_bf16(a1, bfr, acc[1][n], 0, 0, 0);
    }
  }
  const int seg = colbase / NHID;   // uniform per block: 0=q 1=k 2=v
#pragma unroll
  for (int n = 0; n < 4; ++n) {
    int col = colbase + n * 16 + l15;
    int cc = col % NHID;
    float bias = (seg == 0) ? qb[cc] : (seg == 2) ? vb[cc] : 0.0f;
#pragma unroll
    for (int m = 0; m < 2; ++m) {
#pragma unroll
      for (int r = 0; r < 4; ++r) {
        int row = rowbase + m * 16 + lhi * 4 + r;
        float v = acc[m][n][r];
        if (seg == 0) v = (v + bias) * 0.125f;
        else if (seg == 2) v = v + bias;
        out[(size_t)row * N3 + col] = f2bf(v);
      }
    }
  }
}

// ---- transpose V (cols 1536..2303 of qkv) -> Vt [96][64][1024] bf16 ----
__global__ __launch_bounds__(256) void k_vt(const unsigned short* __restrict__ qkvb,
                                            unsigned short* __restrict__ Vt) {
  __shared__ unsigned short tile[32][33];
  int s0 = blockIdx.x * 32;  // over 1024
  int d0 = blockIdx.y * 32;  // over 64
  int bh = blockIdx.z;       // 0..95
  int b = bh / NH;
  int hcol = (bh % NH) * ND;
  int tx = threadIdx.x & 31, ty = threadIdx.x >> 5;
#pragma unroll
  for (int p = 0; p < 4; ++p) {
    int s = s0 + ty + 8*p;
    tile[ty + 8*p][tx] = qkvb[(size_t)(b * NS + s) * N3 + 2 * NHID + hcol + d0 + tx];
  }
  __syncthreads();
#pragma unroll
  for (int p = 0; p < 4; ++p) {
    int d = d0 + ty + 8*p;
    Vt[((size_t)bh * ND + d) * NS + s0 + tx] = tile[tx][ty + 8*p];
  }
}

// ---- fused attention: one block per (qtile16, h, b), 8 waves x 128 keys ----
// Decoupled phases for MLP: (A) K loads + MFMA -> sc[8] in regs;
// (B) ALL rel/rel2 float4 loads issued back-to-back into reg arrays (16 KB
// in flight per wave); (C) exp + pack + LDS. Mask via pre-packed u64 bits.
// p_lds swizzle col ^ (l15<<2); p_lds reused as f32 ctx partials at the end.
__global__ __launch_bounds__(512, 4) void k_attn(const unsigned short* __restrict__ qkvb,
                                                 const unsigned short* __restrict__ Vt,
                                                 const float* __restrict__ relp,
                                                 const float* __restrict__ rel2,
                                                 const unsigned long long* __restrict__ mbits,
                                                 float* __restrict__ outp) {
  __shared__ __align__(16) unsigned short p_lds[16][1024];  // 32 KB; reused as f32[8][16][64]
  __shared__ float rs_lds[8][16];
  __shared__ float inv_lds[16];

  const int qt = blockIdx.x, h = blockIdx.y, b = blockIdx.z;
  const int t = threadIdx.x, w = t >> 6, l = t & 63, l15 = l & 15, lhi = l >> 4;
  const int bh = b * NH + h;
  const int swz = l15 << 2;

  // Q fragments (16 rows x 64 d); q already scaled+biased in k_qkv
  const unsigned short* qrowp = qkvb + (size_t)(b * NS + qt * 16 + l15) * N3 + h * ND;
  short8 qa0 = *(const short8*)(qrowp + lhi * 8);
  short8 qa1 = *(const short8*)(qrowp + 32 + lhi * 8);

  const float* relrow  = relp + ((size_t)bh * NS + qt * 16 + l15) * NS;
  const float* rel2row = rel2 + ((size_t)bh * NS + qt * 16 + l15) * NS;
  const unsigned long long mw0 = mbits[b * 16 + w * 2];
  const unsigned long long mw1 = mbits[b * 16 + w * 2 + 1];

  // phase A: raw scores for this wave's 128 keys, kept in registers
  f32x4 sc[8];
#pragma unroll
  for (int c = 0; c < 8; ++c) {
    int kb = w * 128 + c * 16;
    const unsigned short* krowp = qkvb + (size_t)(b * NS + kb + l15) * N3 + NHID + h * ND;
    short8 kf0 = *(const short8*)(krowp + lhi * 8);
    short8 kf1 = *(const short8*)(krowp + 32 + lhi * 8);
    f32x4 s = {};
    s = __builtin_amdgcn_mfma_f32_16x16x32_bf16(kf0, qa0, s, 0, 0, 0);
    s = __builtin_amdgcn_mfma_f32_16x16x32_bf16(kf1, qa1, s, 0, 0, 0);
    sc[c] = s;
  }

  // phase B: all rel/rel2 loads in flight
  float4 R[8], R2[8];
#pragma unroll
  for (int c = 0; c < 8; ++c) {
    int kc = w * 128 + c * 16 + lhi * 4;
    R[c]  = *(const float4*)(relrow + kc);
    R2[c] = *(const float4*)(rel2row + kc);
  }

  // phase C: exp + pack + LDS
  float rs = 0.f;
#pragma unroll
  for (int c = 0; c < 8; ++c) {
    int kc = w * 128 + c * 16 + lhi * 4;
    unsigned long long wsel = (c < 4) ? mw0 : mw1;
    int mb = (int)((wsel >> ((c & 3) * 16 + lhi * 4)) & 0xFull);
    float p0 = (mb & 1) ? 0.f : __expf(sc[c][0] + R[c].x + R2[c].x);
    float p1 = (mb & 2) ? 0.f : __expf(sc[c][1] + R[c].y + R2[c].y);
    float p2 = (mb & 4) ? 0.f : __expf(sc[c][2] + R[c].z + R2[c].z);
    float p3 = (mb & 8) ? 0.f : __expf(sc[c][3] + R[c].w + R2[c].w);
    rs += (p0 + p1) + (p2 + p3);
    ushort4 pw;
    pw.x = f2bf(p0); pw.y = f2bf(p1); pw.z = f2bf(p2); pw.w = f2bf(p3);
    *(ushort4*)(&p_lds[l15][kc ^ swz]) = pw;
  }

  // row sums: reduce lhi-groups within wave, then across 8 waves
  rs += __shfl_xor(rs, 16);
  rs += __shfl_xor(rs, 32);
  if (lhi == 0) rs_lds[w][l15] = rs;
  __syncthreads();
  if (t < 16) {
    float s = 0.f;
#pragma unroll
    for (int ww = 0; ww < 8; ++ww) s += rs_lds[ww][t];
    inv_lds[t] = 1.0f / s;
  }
  __syncthreads();

  // probs out first (stores overlap the PV MFMAs that follow)
  {
    float* probs = outp + (size_t)NB * NS * NHID;
#pragma unroll
    for (int rr = 0; rr < 2; ++rr) {
      int row = w * 2 + rr;
      float inv = inv_lds[row];
      int sz = row << 2;
      size_t base = ((size_t)bh * NS + qt * 16 + row) * NS;
#pragma unroll
      for (int i = 0; i < 4; ++i) {
        int col = 4 * l + 256 * i;
        ushort4 pv = *(const ushort4*)(&p_lds[row][col ^ sz]);
        float4 o;
        o.x = bf2f(pv.x) * inv;
        o.y = bf2f(pv.y) * inv;
        o.z = bf2f(pv.z) * inv;
        o.w = bf2f(pv.w) * inv;
        *(float4*)(&probs[base + col]) = o;
      }
    }
  }

  // phase 2: PV over own 128 keys, all 16 q-rows x 64 d (partials in regs)
  f32x4 cacc[4] = {};
  const unsigned short* vtb = Vt + (size_t)bh * ND * NS;
#pragma unroll
  for (int c2 = 0; c2 < 4; ++c2) {
    int kb2 = w * 128 + c2 * 32 + lhi * 8;
    ushort4 pa0 = *(const ushort4*)(&p_lds[l15][kb2 ^ swz]);
    ushort4 pa1 = *(const ushort4*)(&p_lds[l15][(kb2 + 4) ^ swz]);
    short8 pa;
    pa[0] = pa0.x; pa[1] = pa0.y; pa[2] = pa0.z; pa[3] = pa0.w;
    pa[4] = pa1.x; pa[5] = pa1.y; pa[6] = pa1.z; pa[7] = pa1.w;
#pragma unroll
    for (int n = 0; n < 4; ++n) {
      short8 vf = *(const short8*)(vtb + (size_t)(n * 16 + l15) * NS + kb2);
      cacc[n] = __builtin_amdgcn_mfma_f32_16x16x32_bf16(pa, vf, cacc[n], 0, 0, 0);
    }
  }

  // all P reads done -> reuse p_lds as f32 ctx partials [8][16][64]
  __syncthreads();
  float* cpart = (float*)p_lds;
#pragma unroll
  for (int n = 0; n < 4; ++n)
#pragma unroll
    for (int r = 0; r < 4; ++r)
      cpart[w * 1024 + (lhi * 4 + r) * 64 + n * 16 + l15] = cacc[n][r];
  __syncthreads();

  // reduce 8 partials, scale, store ctx [B,S,HID]
#pragma unroll
  for (int i = 0; i < 2; ++i) {
    int idx = t + 512 * i;
    int q = idx >> 6, d = idx & 63;
    float s = 0.f;
#pragma unroll
    for (int ww = 0; ww < 8; ++ww) s += cpart[ww * 1024 + idx];
    outp[(size_t)(b * NS + qt * 16 + q) * NHID + h * ND + d] = s * inv_lds[q];
  }
}

extern "C" void kernel_launch(void* const* d_in, const int* in_sizes, int n_in,
                              void* d_out, int out_size, void* d_ws, size_t ws_size,
                              hipStream_t stream) {
  const float* hidden = (const float*)d_in[0];
  const int* mask = (const int*)d_in[1];
  const float* relp = (const float*)d_in[2];
  const float* rel2 = (const float*)d_in[3];
  const float* Wq = (const float*)d_in[4];
  const float* qb = (const float*)d_in[5];
  const float* vb = (const float*)d_in[6];
  float* out = (float*)d_out;

  const size_t OFF_AHS = 0;                       // 8192*768*2
  const size_t OFF_WT  = 12582912;                // 2304*768*2
  const size_t OFF_QKV = 16121856;                // 8192*2304*2
  const size_t OFF_VT  = 53870592;                // 96*64*1024*2
  const size_t OFF_MB  = 66453504;                // 8*16*8 = 1024
  if (ws_size < 66454528) return;

  char* ws = (char*)d_ws;
  unsigned short* Ahs  = (unsigned short*)(ws + OFF_AHS);
  unsigned short* Wt   = (unsigned short*)(ws + OFF_WT);
  unsigned short* qkvb = (unsigned short*)(ws + OFF_QKV);
  unsigned short* Vt   = (unsigned short*)(ws + OFF_VT);
  unsigned long long* mb = (unsigned long long*)(ws + OFF_MB);

  k_cast<<<dim3(6144), dim3(256), 0, stream>>>(hidden, Ahs, (NB * NS * NHID) / 4);
  k_mask<<<dim3(8), dim3(1024), 0, stream>>>(mask, mb);
  k_wt<<<dim3(24, 72), dim3(256), 0, stream>>>(Wq, Wt);
  k_qkv<<<dim3(64, 36), dim3(256), 0, stream>>>(Ahs, Wt, qb, vb, qkvb);
  k_vt<<<dim3(32, 2, 96), dim3(256), 0, stream>>>(qkvb, Vt);
  k_attn<<<dim3(64, 12, 8), dim3(512), 0, stream>>>(qkvb, Vt, relp, rel2, mb, out);
}

// Round 5
// 583.414 us; speedup vs baseline: 1.1602x; 1.0394x over previous
//
#include <hip/hip_runtime.h>
#include <hip/hip_bf16.h>

typedef __attribute__((ext_vector_type(8))) short short8;
typedef __attribute__((ext_vector_type(4))) float f32x4;

#define NB 8
#define NS 1024
#define NH 12
#define ND 64
#define NHID 768
#define N3 2304

#define SBAR() __builtin_amdgcn_sched_barrier(0)

__device__ __forceinline__ unsigned short f2bf(float f) {
  __hip_bfloat16 h = __float2bfloat16(f);
  return *reinterpret_cast<unsigned short*>(&h);
}
__device__ __forceinline__ float bf2f(unsigned short u) {
  __hip_bfloat16 h;
  *reinterpret_cast<unsigned short*>(&h) = u;
  return __bfloat162float(h);
}

// ---- cast hidden f32 -> bf16 ----
__global__ void k_cast(const float* __restrict__ in, unsigned short* __restrict__ out, int n4) {
  int i = blockIdx.x * blockDim.x + threadIdx.x;
  if (i >= n4) return;
  float4 v = ((const float4*)in)[i];
  ushort4 o;
  o.x = f2bf(v.x); o.y = f2bf(v.y); o.z = f2bf(v.z); o.w = f2bf(v.w);
  ((ushort4*)out)[i] = o;
}

// ---- pack mask [B][S] int -> bitmask [B][16] u64 ----
__global__ void k_mask(const int* __restrict__ mask, unsigned long long* __restrict__ bits) {
  int b = blockIdx.x, t = threadIdx.x;
  unsigned long long bal = __ballot(mask[b * NS + t] != 0);
  if ((t & 63) == 0) bits[b * 16 + (t >> 6)] = bal;
}

// ---- transpose-cast W [768][2304] f32 -> Wt [2304][768] bf16 ----
__global__ __launch_bounds__(256) void k_wt(const float* __restrict__ W, unsigned short* __restrict__ Wt) {
  __shared__ float tile[32][33];
  int r0 = blockIdx.x * 32;   // over 768
  int c0 = blockIdx.y * 32;   // over 2304
  int tx = threadIdx.x & 31, ty = threadIdx.x >> 5;
#pragma unroll
  for (int p = 0; p < 4; ++p)
    tile[ty + 8*p][tx] = W[(size_t)(r0 + ty + 8*p) * N3 + c0 + tx];
  __syncthreads();
#pragma unroll
  for (int p = 0; p < 4; ++p)
    Wt[(size_t)(c0 + ty + 8*p) * NHID + r0 + tx] = f2bf(tile[tx][ty + 8*p]);
}

// ---- QKV GEMM: [8192][768]bf16 @ Wt[2304][768]bf16 -> qkv [8192][2304]bf16 ----
__global__ __launch_bounds__(256) void k_qkv(const unsigned short* __restrict__ A,
                                             const unsigned short* __restrict__ Wt,
                                             const float* __restrict__ qb,
                                             const float* __restrict__ vb,
                                             unsigned short* __restrict__ out) {
  const int t = threadIdx.x;
  const int w = t >> 6, l = t & 63, l15 = l & 15, lhi = l >> 4;
  const int rowbase = blockIdx.x * 128 + w * 32;
  const int colbase = blockIdx.y * 64;

  f32x4 acc[2][4] = {};
  const unsigned short* arow0 = A + (size_t)(rowbase + l15) * NHID;
  const unsigned short* arow1 = A + (size_t)(rowbase + 16 + l15) * NHID;
  const unsigned short* wrows[4];
#pragma unroll
  for (int n = 0; n < 4; ++n)
    wrows[n] = Wt + (size_t)(colbase + n * 16 + l15) * NHID;

  for (int k0 = 0; k0 < NHID; k0 += 32) {
    short8 a0 = *(const short8*)(arow0 + k0 + lhi * 8);
    short8 a1 = *(const short8*)(arow1 + k0 + lhi * 8);
#pragma unroll
    for (int n = 0; n < 4; ++n) {
      short8 bfr = *(const short8*)(wrows[n] + k0 + lhi * 8);
      acc[0][n] = __builtin_amdgcn_mfma_f32_16x16x32_bf16(a0, bfr, acc[0][n], 0, 0, 0);
      acc[1][n] = __builtin_amdgcn_mfma_f32_16x16x32_bf16(a1, bfr, acc[1][n], 0, 0, 0);
    }
  }
  const int seg = colbase / NHID;   // uniform per block: 0=q 1=k 2=v
#pragma unroll
  for (int n = 0; n < 4; ++n) {
    int col = colbase + n * 16 + l15;
    int cc = col % NHID;
    float bias = (seg == 0) ? qb[cc] : (seg == 2) ? vb[cc] : 0.0f;
#pragma unroll
    for (int m = 0; m < 2; ++m) {
#pragma unroll
      for (int r = 0; r < 4; ++r) {
        int row = rowbase + m * 16 + lhi * 4 + r;
        float v = acc[m][n][r];
        if (seg == 0) v = (v + bias) * 0.125f;
        else if (seg == 2) v = v + bias;
        out[(size_t)row * N3 + col] = f2bf(v);
      }
    }
  }
}

// ---- transpose V (cols 1536..2303 of qkv) -> Vt [96][64][1024] bf16 ----
__global__ __launch_bounds__(256) void k_vt(const unsigned short* __restrict__ qkvb,
                                            unsigned short* __restrict__ Vt) {
  __shared__ unsigned short tile[32][33];
  int s0 = blockIdx.x * 32;  // over 1024
  int d0 = blockIdx.y * 32;  // over 64
  int bh = blockIdx.z;       // 0..95
  int b = bh / NH;
  int hcol = (bh % NH) * ND;
  int tx = threadIdx.x & 31, ty = threadIdx.x >> 5;
#pragma unroll
  for (int p = 0; p < 4; ++p) {
    int s = s0 + ty + 8*p;
    tile[ty + 8*p][tx] = qkvb[(size_t)(b * NS + s) * N3 + 2 * NHID + hcol + d0 + tx];
  }
  __syncthreads();
#pragma unroll
  for (int p = 0; p < 4; ++p) {
    int d = d0 + ty + 8*p;
    Vt[((size_t)bh * ND + d) * NS + s0 + tx] = tile[tx][ty + 8*p];
  }
}

// ---- fused attention: one block per (qtile16, h, b), 8 waves x 128 keys ----
// sched_barrier(0)-fenced load clusters force deep MLP:
//   K1(8 loads) K2(8) | MFMA c0-3 | L1(8 rel loads) | MFMA c4-7 | L2(8) | process
// Swapped QK^T: lane q-row = l15, keys kc..kc+3 -> rel float4 loads.
// p_lds swizzle col ^ (l15<<2); reused as f32 ctx partials at the end.
__global__ __launch_bounds__(512, 4) void k_attn(const unsigned short* __restrict__ qkvb,
                                                 const unsigned short* __restrict__ Vt,
                                                 const float* __restrict__ relp,
                                                 const float* __restrict__ rel2,
                                                 const unsigned long long* __restrict__ mbits,
                                                 float* __restrict__ outp) {
  __shared__ __align__(16) unsigned short p_lds[16][1024];  // 32 KB; reused as f32[8][16][64]
  __shared__ float rs_lds[8][16];
  __shared__ float inv_lds[16];

  const int qt = blockIdx.x, h = blockIdx.y, b = blockIdx.z;
  const int t = threadIdx.x, w = t >> 6, l = t & 63, l15 = l & 15, lhi = l >> 4;
  const int bh = b * NH + h;
  const int swz = l15 << 2;

  // Q fragments (16 rows x 64 d); q already scaled+biased in k_qkv
  const unsigned short* qrowp = qkvb + (size_t)(b * NS + qt * 16 + l15) * N3 + h * ND;
  short8 qa0 = *(const short8*)(qrowp + lhi * 8);
  short8 qa1 = *(const short8*)(qrowp + 32 + lhi * 8);

  const float* relrow  = relp + ((size_t)bh * NS + qt * 16 + l15) * NS;
  const float* rel2row = rel2 + ((size_t)bh * NS + qt * 16 + l15) * NS;
  const unsigned long long mw0 = mbits[b * 16 + w * 2];
  const unsigned long long mw1 = mbits[b * 16 + w * 2 + 1];

  // ---- fenced pipeline ----
  short8 kf[8][2];
  SBAR();
#pragma unroll
  for (int c = 0; c < 4; ++c) {            // K1
    const unsigned short* krowp = qkvb + (size_t)(b * NS + w * 128 + c * 16 + l15) * N3 + NHID + h * ND;
    kf[c][0] = *(const short8*)(krowp + lhi * 8);
    kf[c][1] = *(const short8*)(krowp + 32 + lhi * 8);
  }
  SBAR();
#pragma unroll
  for (int c = 4; c < 8; ++c) {            // K2
    const unsigned short* krowp = qkvb + (size_t)(b * NS + w * 128 + c * 16 + l15) * N3 + NHID + h * ND;
    kf[c][0] = *(const short8*)(krowp + lhi * 8);
    kf[c][1] = *(const short8*)(krowp + 32 + lhi * 8);
  }
  SBAR();
  f32x4 sc[8];
#pragma unroll
  for (int c = 0; c < 4; ++c) {            // M1 (waits K1 only)
    f32x4 s = {};
    s = __builtin_amdgcn_mfma_f32_16x16x32_bf16(kf[c][0], qa0, s, 0, 0, 0);
    s = __builtin_amdgcn_mfma_f32_16x16x32_bf16(kf[c][1], qa1, s, 0, 0, 0);
    sc[c] = s;
  }
  SBAR();
  float4 R[8], R2[8];
#pragma unroll
  for (int c = 0; c < 4; ++c) {            // L1
    int kc = w * 128 + c * 16 + lhi * 4;
    R[c]  = *(const float4*)(relrow + kc);
    R2[c] = *(const float4*)(rel2row + kc);
  }
  SBAR();
#pragma unroll
  for (int c = 4; c < 8; ++c) {            // M2
    f32x4 s = {};
    s = __builtin_amdgcn_mfma_f32_16x16x32_bf16(kf[c][0], qa0, s, 0, 0, 0);
    s = __builtin_amdgcn_mfma_f32_16x16x32_bf16(kf[c][1], qa1, s, 0, 0, 0);
    sc[c] = s;
  }
  SBAR();
#pragma unroll
  for (int c = 4; c < 8; ++c) {            // L2
    int kc = w * 128 + c * 16 + lhi * 4;
    R[c]  = *(const float4*)(relrow + kc);
    R2[c] = *(const float4*)(rel2row + kc);
  }
  SBAR();

  // process: exp + pack + LDS
  float rs = 0.f;
#pragma unroll
  for (int c = 0; c < 8; ++c) {
    int kc = w * 128 + c * 16 + lhi * 4;
    unsigned long long wsel = (c < 4) ? mw0 : mw1;
    int mb = (int)((wsel >> ((c & 3) * 16 + lhi * 4)) & 0xFull);
    float p0 = (mb & 1) ? 0.f : __expf(sc[c][0] + R[c].x + R2[c].x);
    float p1 = (mb & 2) ? 0.f : __expf(sc[c][1] + R[c].y + R2[c].y);
    float p2 = (mb & 4) ? 0.f : __expf(sc[c][2] + R[c].z + R2[c].z);
    float p3 = (mb & 8) ? 0.f : __expf(sc[c][3] + R[c].w + R2[c].w);
    rs += (p0 + p1) + (p2 + p3);
    ushort4 pw;
    pw.x = f2bf(p0); pw.y = f2bf(p1); pw.z = f2bf(p2); pw.w = f2bf(p3);
    *(ushort4*)(&p_lds[l15][kc ^ swz]) = pw;
  }

  // row sums: reduce lhi-groups within wave, then across 8 waves
  rs += __shfl_xor(rs, 16);
  rs += __shfl_xor(rs, 32);
  if (lhi == 0) rs_lds[w][l15] = rs;
  __syncthreads();
  if (t < 16) {
    float s = 0.f;
#pragma unroll
    for (int ww = 0; ww < 8; ++ww) s += rs_lds[ww][t];
    inv_lds[t] = 1.0f / s;
  }
  __syncthreads();

  // probs out first (stores overlap the PV MFMAs that follow)
  {
    float* probs = outp + (size_t)NB * NS * NHID;
#pragma unroll
    for (int rr = 0; rr < 2; ++rr) {
      int row = w * 2 + rr;
      float inv = inv_lds[row];
      int sz = row << 2;
      size_t base = ((size_t)bh * NS + qt * 16 + row) * NS;
#pragma unroll
      for (int i = 0; i < 4; ++i) {
        int col = 4 * l + 256 * i;
        ushort4 pv = *(const ushort4*)(&p_lds[row][col ^ sz]);
        float4 o;
        o.x = bf2f(pv.x) * inv;
        o.y = bf2f(pv.y) * inv;
        o.z = bf2f(pv.z) * inv;
        o.w = bf2f(pv.w) * inv;
        *(float4*)(&probs[base + col]) = o;
      }
    }
  }

  // phase 2: PV over own 128 keys, all 16 q-rows x 64 d (partials in regs)
  f32x4 cacc[4] = {};
  const unsigned short* vtb = Vt + (size_t)bh * ND * NS;
#pragma unroll
  for (int c2 = 0; c2 < 4; ++c2) {
    int kb2 = w * 128 + c2 * 32 + lhi * 8;
    ushort4 pa0 = *(const ushort4*)(&p_lds[l15][kb2 ^ swz]);
    ushort4 pa1 = *(const ushort4*)(&p_lds[l15][(kb2 + 4) ^ swz]);
    short8 pa;
    pa[0] = pa0.x; pa[1] = pa0.y; pa[2] = pa0.z; pa[3] = pa0.w;
    pa[4] = pa1.x; pa[5] = pa1.y; pa[6] = pa1.z; pa[7] = pa1.w;
#pragma unroll
    for (int n = 0; n < 4; ++n) {
      short8 vf = *(const short8*)(vtb + (size_t)(n * 16 + l15) * NS + kb2);
      cacc[n] = __builtin_amdgcn_mfma_f32_16x16x32_bf16(pa, vf, cacc[n], 0, 0, 0);
    }
  }

  // all P reads done -> reuse p_lds as f32 ctx partials [8][16][64]
  __syncthreads();
  float* cpart = (float*)p_lds;
#pragma unroll
  for (int n = 0; n < 4; ++n)
#pragma unroll
    for (int r = 0; r < 4; ++r)
      cpart[w * 1024 + (lhi * 4 + r) * 64 + n * 16 + l15] = cacc[n][r];
  __syncthreads();

  // reduce 8 partials, scale, store ctx [B,S,HID]
#pragma unroll
  for (int i = 0; i < 2; ++i) {
    int idx = t + 512 * i;
    int q = idx >> 6, d = idx & 63;
    float s = 0.f;
#pragma unroll
    for (int ww = 0; ww < 8; ++ww) s += cpart[ww * 1024 + idx];
    outp[(size_t)(b * NS + qt * 16 + q) * NHID + h * ND + d] = s * inv_lds[q];
  }
}

extern "C" void kernel_launch(void* const* d_in, const int* in_sizes, int n_in,
                              void* d_out, int out_size, void* d_ws, size_t ws_size,
                              hipStream_t stream) {
  const float* hidden = (const float*)d_in[0];
  const int* mask = (const int*)d_in[1];
  const float* relp = (const float*)d_in[2];
  const float* rel2 = (const float*)d_in[3];
  const float* Wq = (const float*)d_in[4];
  const float* qb = (const float*)d_in[5];
  const float* vb = (const float*)d_in[6];
  float* out = (float*)d_out;

  const size_t OFF_AHS = 0;                       // 8192*768*2
  const size_t OFF_WT  = 12582912;                // 2304*768*2
  const size_t OFF_QKV = 16121856;                // 8192*2304*2
  const size_t OFF_VT  = 53870592;                // 96*64*1024*2
  const size_t OFF_MB  = 66453504;                // 8*16*8 = 1024
  if (ws_size < 66454528) return;

  char* ws = (char*)d_ws;
  unsigned short* Ahs  = (unsigned short*)(ws + OFF_AHS);
  unsigned short* Wt   = (unsigned short*)(ws + OFF_WT);
  unsigned short* qkvb = (unsigned short*)(ws + OFF_QKV);
  unsigned short* Vt   = (unsigned short*)(ws + OFF_VT);
  unsigned long long* mb = (unsigned long long*)(ws + OFF_MB);

  k_cast<<<dim3(6144), dim3(256), 0, stream>>>(hidden, Ahs, (NB * NS * NHID) / 4);
  k_mask<<<dim3(8), dim3(1024), 0, stream>>>(mask, mb);
  k_wt<<<dim3(24, 72), dim3(256), 0, stream>>>(Wq, Wt);
  k_qkv<<<dim3(64, 36), dim3(256), 0, stream>>>(Ahs, Wt, qb, vb, qkvb);
  k_vt<<<dim3(32, 2, 96), dim3(256), 0, stream>>>(qkvb, Vt);
  k_attn<<<dim3(64, 12, 8), dim3(512), 0, stream>>>(qkvb, Vt, relp, rel2, mb, out);
}

// Round 6
// 549.664 us; speedup vs baseline: 1.2315x; 1.0614x over previous
//
#include <hip/hip_runtime.h>
#include <hip/hip_bf16.h>

typedef __attribute__((ext_vector_type(8))) short short8;
typedef __attribute__((ext_vector_type(4))) float f32x4;

#define NB 8
#define NS 1024
#define NH 12
#define ND 64
#define NHID 768
#define N3 2304

#define SBAR() __builtin_amdgcn_sched_barrier(0)

__device__ __forceinline__ unsigned short f2bf(float f) {
  __hip_bfloat16 h = __float2bfloat16(f);
  return *reinterpret_cast<unsigned short*>(&h);
}
__device__ __forceinline__ float bf2f(unsigned short u) {
  __hip_bfloat16 h;
  *reinterpret_cast<unsigned short*>(&h) = u;
  return __bfloat162float(h);
}

// ---- cast hidden f32 -> bf16 ----
__global__ void k_cast(const float* __restrict__ in, unsigned short* __restrict__ out, int n4) {
  int i = blockIdx.x * blockDim.x + threadIdx.x;
  if (i >= n4) return;
  float4 v = ((const float4*)in)[i];
  ushort4 o;
  o.x = f2bf(v.x); o.y = f2bf(v.y); o.z = f2bf(v.z); o.w = f2bf(v.w);
  ((ushort4*)out)[i] = o;
}

// ---- pack mask [B][S] int -> bitmask [B][16] u64 ----
__global__ void k_mask(const int* __restrict__ mask, unsigned long long* __restrict__ bits) {
  int b = blockIdx.x, t = threadIdx.x;
  unsigned long long bal = __ballot(mask[b * NS + t] != 0);
  if ((t & 63) == 0) bits[b * 16 + (t >> 6)] = bal;
}

// ---- transpose-cast W [768][2304] f32 -> Wt [2304][768] bf16 ----
__global__ __launch_bounds__(256) void k_wt(const float* __restrict__ W, unsigned short* __restrict__ Wt) {
  __shared__ float tile[32][33];
  int r0 = blockIdx.x * 32;   // over 768
  int c0 = blockIdx.y * 32;   // over 2304
  int tx = threadIdx.x & 31, ty = threadIdx.x >> 5;
#pragma unroll
  for (int p = 0; p < 4; ++p)
    tile[ty + 8*p][tx] = W[(size_t)(r0 + ty + 8*p) * N3 + c0 + tx];
  __syncthreads();
#pragma unroll
  for (int p = 0; p < 4; ++p)
    Wt[(size_t)(c0 + ty + 8*p) * NHID + r0 + tx] = f2bf(tile[tx][ty + 8*p]);
}

// ---- QKV GEMM: [8192][768]bf16 @ Wt[2304][768]bf16 -> qkv [8192][2304]bf16 ----
__global__ __launch_bounds__(256) void k_qkv(const unsigned short* __restrict__ A,
                                             const unsigned short* __restrict__ Wt,
                                             const float* __restrict__ qb,
                                             const float* __restrict__ vb,
                                             unsigned short* __restrict__ out) {
  const int t = threadIdx.x;
  const int w = t >> 6, l = t & 63, l15 = l & 15, lhi = l >> 4;
  const int rowbase = blockIdx.x * 128 + w * 32;
  const int colbase = blockIdx.y * 64;

  f32x4 acc[2][4] = {};
  const unsigned short* arow0 = A + (size_t)(rowbase + l15) * NHID;
  const unsigned short* arow1 = A + (size_t)(rowbase + 16 + l15) * NHID;
  const unsigned short* wrows[4];
#pragma unroll
  for (int n = 0; n < 4; ++n)
    wrows[n] = Wt + (size_t)(colbase + n * 16 + l15) * NHID;

  for (int k0 = 0; k0 < NHID; k0 += 32) {
    short8 a0 = *(const short8*)(arow0 + k0 + lhi * 8);
    short8 a1 = *(const short8*)(arow1 + k0 + lhi * 8);
#pragma unroll
    for (int n = 0; n < 4; ++n) {
      short8 bfr = *(const short8*)(wrows[n] + k0 + lhi * 8);
      acc[0][n] = __builtin_amdgcn_mfma_f32_16x16x32_bf16(a0, bfr, acc[0][n], 0, 0, 0);
      acc[1][n] = __builtin_amdgcn_mfma_f32_16x16x32_bf16(a1, bfr, acc[1][n], 0, 0, 0);
    }
  }
  const int seg = colbase / NHID;   // uniform per block: 0=q 1=k 2=v
#pragma unroll
  for (int n = 0; n < 4; ++n) {
    int col = colbase + n * 16 + l15;
    int cc = col % NHID;
    float bias = (seg == 0) ? qb[cc] : (seg == 2) ? vb[cc] : 0.0f;
#pragma unroll
    for (int m = 0; m < 2; ++m) {
#pragma unroll
      for (int r = 0; r < 4; ++r) {
        int row = rowbase + m * 16 + lhi * 4 + r;
        float v = acc[m][n][r];
        if (seg == 0) v = (v + bias) * 0.125f;
        else if (seg == 2) v = v + bias;
        out[(size_t)row * N3 + col] = f2bf(v);
      }
    }
  }
}

// ---- transpose V (cols 1536..2303 of qkv) -> Vt [96][64][1024] bf16 ----
__global__ __launch_bounds__(256) void k_vt(const unsigned short* __restrict__ qkvb,
                                            unsigned short* __restrict__ Vt) {
  __shared__ unsigned short tile[32][33];
  int s0 = blockIdx.x * 32;  // over 1024
  int d0 = blockIdx.y * 32;  // over 64
  int bh = blockIdx.z;       // 0..95
  int b = bh / NH;
  int hcol = (bh % NH) * ND;
  int tx = threadIdx.x & 31, ty = threadIdx.x >> 5;
#pragma unroll
  for (int p = 0; p < 4; ++p) {
    int s = s0 + ty + 8*p;
    tile[ty + 8*p][tx] = qkvb[(size_t)(b * NS + s) * N3 + 2 * NHID + hcol + d0 + tx];
  }
  __syncthreads();
#pragma unroll
  for (int p = 0; p < 4; ++p) {
    int d = d0 + ty + 8*p;
    Vt[((size_t)bh * ND + d) * NS + s0 + tx] = tile[tx][ty + 8*p];
  }
}

// ---- fused attention: one block per (qtile16, h, b), 4 waves x 256 keys ----
// 4 blocks/CU resident (33 KB LDS); rolling 1-ahead prefetch over 16 c-iters
// with sched_barrier fences. Swapped QK^T: lane q-row = l15, keys kc..kc+3.
// p_lds swizzle col ^ (l15<<2); reused as f32 ctx partials [4][16][64].
__global__ __launch_bounds__(256, 4) void k_attn(const unsigned short* __restrict__ qkvb,
                                                 const unsigned short* __restrict__ Vt,
                                                 const float* __restrict__ relp,
                                                 const float* __restrict__ rel2,
                                                 const unsigned long long* __restrict__ mbits,
                                                 float* __restrict__ outp) {
  __shared__ __align__(16) unsigned short p_lds[16][1024];  // 32 KB; reused as f32[4][16][64]
  __shared__ float rs_lds[4][16];
  __shared__ float inv_lds[16];

  const int qt = blockIdx.x, h = blockIdx.y, b = blockIdx.z;
  const int t = threadIdx.x, w = t >> 6, l = t & 63, l15 = l & 15, lhi = l >> 4;
  const int bh = b * NH + h;
  const int swz = l15 << 2;
  const int wk = w * 256;                       // this wave's key base

  // Q fragments (16 rows x 64 d); q already scaled+biased in k_qkv
  const unsigned short* qrowp = qkvb + (size_t)(b * NS + qt * 16 + l15) * N3 + h * ND;
  short8 qa0 = *(const short8*)(qrowp + lhi * 8);
  short8 qa1 = *(const short8*)(qrowp + 32 + lhi * 8);

  const float* relrow  = relp + ((size_t)bh * NS + qt * 16 + l15) * NS;
  const float* rel2row = rel2 + ((size_t)bh * NS + qt * 16 + l15) * NS;
  const unsigned long long* mwp = mbits + b * 16 + w * 4;
  unsigned long long mw[4];
#pragma unroll
  for (int i = 0; i < 4; ++i) mw[i] = mwp[i];

  const unsigned short* kbase = qkvb + (size_t)(b * NS + l15) * N3 + NHID + h * ND;

  // ---- phase 1: rolling 2-stage pipeline over 16 c-iters ----
  short8 k0s[2], k1s[2];
  float4 Ra[2], Rb[2];
  {
    const unsigned short* kr = kbase + (size_t)(wk) * N3;
    k0s[0] = *(const short8*)(kr + lhi * 8);
    k1s[0] = *(const short8*)(kr + 32 + lhi * 8);
    Ra[0] = *(const float4*)(relrow + wk + lhi * 4);
    Rb[0] = *(const float4*)(rel2row + wk + lhi * 4);
  }
  float rs = 0.f;
#pragma unroll
  for (int c = 0; c < 16; ++c) {
    const int cur = c & 1, nxt = cur ^ 1;
    SBAR();
    if (c < 15) {   // issue next stage's loads (stay in flight during compute)
      int kn = wk + (c + 1) * 16;
      const unsigned short* kr = kbase + (size_t)kn * N3;
      k0s[nxt] = *(const short8*)(kr + lhi * 8);
      k1s[nxt] = *(const short8*)(kr + 32 + lhi * 8);
      Ra[nxt] = *(const float4*)(relrow + kn + lhi * 4);
      Rb[nxt] = *(const float4*)(rel2row + kn + lhi * 4);
    }
    SBAR();
    // compute current stage
    f32x4 s = {};
    s = __builtin_amdgcn_mfma_f32_16x16x32_bf16(k0s[cur], qa0, s, 0, 0, 0);
    s = __builtin_amdgcn_mfma_f32_16x16x32_bf16(k1s[cur], qa1, s, 0, 0, 0);
    int kc = wk + c * 16 + lhi * 4;
    int mb = (int)((mw[c >> 2] >> ((c & 3) * 16 + lhi * 4)) & 0xFull);
    float p0 = (mb & 1) ? 0.f : __expf(s[0] + Ra[cur].x + Rb[cur].x);
    float p1 = (mb & 2) ? 0.f : __expf(s[1] + Ra[cur].y + Rb[cur].y);
    float p2 = (mb & 4) ? 0.f : __expf(s[2] + Ra[cur].z + Rb[cur].z);
    float p3 = (mb & 8) ? 0.f : __expf(s[3] + Ra[cur].w + Rb[cur].w);
    rs += (p0 + p1) + (p2 + p3);
    ushort4 pw;
    pw.x = f2bf(p0); pw.y = f2bf(p1); pw.z = f2bf(p2); pw.w = f2bf(p3);
    *(ushort4*)(&p_lds[l15][kc ^ swz]) = pw;
    SBAR();
  }

  // row sums: reduce lhi-groups within wave, then across 4 waves
  rs += __shfl_xor(rs, 16);
  rs += __shfl_xor(rs, 32);
  if (lhi == 0) rs_lds[w][l15] = rs;
  __syncthreads();
  if (t < 16)
    inv_lds[t] = 1.0f / (rs_lds[0][t] + rs_lds[1][t] + rs_lds[2][t] + rs_lds[3][t]);
  __syncthreads();

  // probs out (stores overlap the PV MFMAs that follow): wave w rows 4w..4w+3
  {
    float* probs = outp + (size_t)NB * NS * NHID;
#pragma unroll
    for (int rr = 0; rr < 4; ++rr) {
      int row = w * 4 + rr;
      float inv = inv_lds[row];
      int sz = row << 2;
      size_t base = ((size_t)bh * NS + qt * 16 + row) * NS;
#pragma unroll
      for (int i = 0; i < 4; ++i) {
        int col = 4 * l + 256 * i;
        ushort4 pv = *(const ushort4*)(&p_lds[row][col ^ sz]);
        float4 o;
        o.x = bf2f(pv.x) * inv;
        o.y = bf2f(pv.y) * inv;
        o.z = bf2f(pv.z) * inv;
        o.w = bf2f(pv.w) * inv;
        *(float4*)(&probs[base + col]) = o;
      }
    }
  }

  // phase 2: PV over own 256 keys, all 16 q-rows x 64 d (partials in regs)
  f32x4 cacc[4] = {};
  const unsigned short* vtb = Vt + (size_t)bh * ND * NS;
#pragma unroll
  for (int c2 = 0; c2 < 8; ++c2) {
    int kb2 = wk + c2 * 32 + lhi * 8;
    ushort4 pa0 = *(const ushort4*)(&p_lds[l15][kb2 ^ swz]);
    ushort4 pa1 = *(const ushort4*)(&p_lds[l15][(kb2 + 4) ^ swz]);
    short8 pa;
    pa[0] = pa0.x; pa[1] = pa0.y; pa[2] = pa0.z; pa[3] = pa0.w;
    pa[4] = pa1.x; pa[5] = pa1.y; pa[6] = pa1.z; pa[7] = pa1.w;
#pragma unroll
    for (int n = 0; n < 4; ++n) {
      short8 vf = *(const short8*)(vtb + (size_t)(n * 16 + l15) * NS + kb2);
      cacc[n] = __builtin_amdgcn_mfma_f32_16x16x32_bf16(pa, vf, cacc[n], 0, 0, 0);
    }
  }

  // all P reads done -> reuse p_lds as f32 ctx partials [4][16][64]
  __syncthreads();
  float* cpart = (float*)p_lds;
#pragma unroll
  for (int n = 0; n < 4; ++n)
#pragma unroll
    for (int r = 0; r < 4; ++r)
      cpart[w * 1024 + (lhi * 4 + r) * 64 + n * 16 + l15] = cacc[n][r];
  __syncthreads();

  // reduce 4 partials, scale, store ctx [B,S,HID]
#pragma unroll
  for (int i = 0; i < 4; ++i) {
    int idx = t + 256 * i;
    int q = idx >> 6, d = idx & 63;
    float s = cpart[idx] + cpart[1024 + idx] + cpart[2048 + idx] + cpart[3072 + idx];
    outp[(size_t)(b * NS + qt * 16 + q) * NHID + h * ND + d] = s * inv_lds[q];
  }
}

extern "C" void kernel_launch(void* const* d_in, const int* in_sizes, int n_in,
                              void* d_out, int out_size, void* d_ws, size_t ws_size,
                              hipStream_t stream) {
  const float* hidden = (const float*)d_in[0];
  const int* mask = (const int*)d_in[1];
  const float* relp = (const float*)d_in[2];
  const float* rel2 = (const float*)d_in[3];
  const float* Wq = (const float*)d_in[4];
  const float* qb = (const float*)d_in[5];
  const float* vb = (const float*)d_in[6];
  float* out = (float*)d_out;

  const size_t OFF_AHS = 0;                       // 8192*768*2
  const size_t OFF_WT  = 12582912;                // 2304*768*2
  const size_t OFF_QKV = 16121856;                // 8192*2304*2
  const size_t OFF_VT  = 53870592;                // 96*64*1024*2
  const size_t OFF_MB  = 66453504;                // 8*16*8 = 1024
  if (ws_size < 66454528) return;

  char* ws = (char*)d_ws;
  unsigned short* Ahs  = (unsigned short*)(ws + OFF_AHS);
  unsigned short* Wt   = (unsigned short*)(ws + OFF_WT);
  unsigned short* qkvb = (unsigned short*)(ws + OFF_QKV);
  unsigned short* Vt   = (unsigned short*)(ws + OFF_VT);
  unsigned long long* mb = (unsigned long long*)(ws + OFF_MB);

  k_cast<<<dim3(6144), dim3(256), 0, stream>>>(hidden, Ahs, (NB * NS * NHID) / 4);
  k_mask<<<dim3(8), dim3(1024), 0, stream>>>(mask, mb);
  k_wt<<<dim3(24, 72), dim3(256), 0, stream>>>(Wq, Wt);
  k_qkv<<<dim3(64, 36), dim3(256), 0, stream>>>(Ahs, Wt, qb, vb, qkvb);
  k_vt<<<dim3(32, 2, 96), dim3(256), 0, stream>>>(qkvb, Vt);
  k_attn<<<dim3(64, 12, 8), dim3(256), 0, stream>>>(qkvb, Vt, relp, rel2, mb, out);
}